// Round 12
// baseline (23.003 us; speedup 1.0000x reference)
//
#include <hip/hip_runtime.h>

// Problem: B=4, Q=256, K=256, H=768, D=768, NUM_LEN=100
// s = q + k + emb[lm]  (never materialized; all linear maps distribute)
// ws float layout: qP[1024][8] @0, kP[1024][8] @8192, eP[100][8] @16384,
//                  m16 (u32[4][128][768], f16 k-pairs) @ float offset 32768
#define Hn 768
#define Bn 4
#define Qn 256
#define Kn 256
#define Dn 768
#define WS_KP 8192
#define WS_EP 16384
#define WS_M16 32768

typedef _Float16 h2f __attribute__((ext_vector_type(2)));

__device__ __forceinline__ h2f bc_h2(unsigned u) {
    h2f h;
    __builtin_memcpy(&h, &u, 4);
    return h;
}
__device__ __forceinline__ unsigned pack_h2(float lo, float hi) {
    auto v = __builtin_amdgcn_cvt_pkrtz(lo, hi);   // __fp16 vec2
    unsigned u;
    __builtin_memcpy(&u, &v, 4);
    return u;
}

// ---------------- kernel 1: projections (wave per row) + m->f16 convert -----
// blocks 0..536: projection rows (R7/R10 proven, parallelism > reuse).
// blocks 537..728: convert m (f32) to m16 (f16 k-paired u32), 8 u32/thread.
__global__ __launch_bounds__(256) void proj_kernel(
    const float* __restrict__ q, const float* __restrict__ k,
    const float* __restrict__ emb, const float* __restrict__ W1,
    const float* __restrict__ W2, const float* __restrict__ m,
    float* __restrict__ ws)
{
    if (blockIdx.x >= 537) {
        // ---- m conversion: u32 index base, 8 consecutive (same k2 row) ----
        unsigned* m16 = (unsigned*)(ws + WS_M16);
        int base = ((int)(blockIdx.x - 537) * 256 + (int)threadIdx.x) * 8;
        int b   = base / (128 * Dn);
        int rem = base - b * (128 * Dn);
        int k2  = rem / Dn;
        int d   = rem - k2 * Dn;
        const float* s0 = m + ((size_t)(b * Kn + 2 * k2) * Dn + d);
        const float* s1 = s0 + Dn;
        float4 a0 = *(const float4*)s0, a1 = *(const float4*)(s0 + 4);
        float4 b0 = *(const float4*)s1, b1 = *(const float4*)(s1 + 4);
        uint4 o0, o1;
        o0.x = pack_h2(a0.x, b0.x); o0.y = pack_h2(a0.y, b0.y);
        o0.z = pack_h2(a0.z, b0.z); o0.w = pack_h2(a0.w, b0.w);
        o1.x = pack_h2(a1.x, b1.x); o1.y = pack_h2(a1.y, b1.y);
        o1.z = pack_h2(a1.z, b1.z); o1.w = pack_h2(a1.w, b1.w);
        *(uint4*)(m16 + base)     = o0;
        *(uint4*)(m16 + base + 4) = o1;
        return;
    }
    int wid  = blockIdx.x * 4 + (threadIdx.x >> 6);
    int lane = threadIdx.x & 63;
    const float* src;
    float* dst;
    if (wid < 1024)      { src = q + wid * Hn;            dst = ws + wid * 8; }
    else if (wid < 2048) { src = k + (wid - 1024) * Hn;   dst = ws + WS_KP + (wid - 1024) * 8; }
    else {
        int r = wid - 2048;
        if (r >= 100) return;
        src = emb + r * Hn; dst = ws + WS_EP + r * 8;
    }
    float acc[6] = {0.f, 0.f, 0.f, 0.f, 0.f, 0.f};
    #pragma unroll
    for (int i = 0; i < 3; ++i) {
        int h = i * 256 + lane * 4;
        float4 x  = *(const float4*)&src[h];
        float4 w1 = *(const float4*)&W1[h];
        acc[0] += x.x * w1.x + x.y * w1.y + x.z * w1.z + x.w * w1.w;
        #pragma unroll
        for (int c = 0; c < 5; ++c) {
            float4 w2 = *(const float4*)&W2[c * Hn + h];
            acc[1 + c] += x.x * w2.x + x.y * w2.y + x.z * w2.z + x.w * w2.w;
        }
    }
    #pragma unroll
    for (int j = 0; j < 6; ++j) {
        float v = acc[j];
        #pragma unroll
        for (int off = 32; off > 0; off >>= 1)
            v += __shfl_xor(v, off, 64);
        if (lane == 0) dst[j] = v;
    }
}

// ---------------- kernel 2: fused score + softmax + PV ----------------------
// block = (b:4, qt:32 [8 q rows], dt:6 [128 d cols]) = 768 blocks, 256 thr.
// Score phase: WAVE per q-row (2 rows/wave), all-shfl softmax, no max-shift,
// lm/am hoisted; p packed to f16 pairs in LDS (even lanes, shfl_down+pkrtz).
// 5-class scores balanced across dt-replicas (k-slice [dt*43, ...)).
// PV phase: f16 k-paired operands via v_dot2_f32_f16 — half the global/LDS
// bytes of the f32 version at the same VALU instruction count.
__global__ __launch_bounds__(256, 4) void fused_kernel(
    const float* __restrict__ ws_proj, const float* __restrict__ am,
    const int* __restrict__ lm, const float* __restrict__ b1,
    const float* __restrict__ b2, float* __restrict__ scores_out,
    float* __restrict__ content_out)
{
    __shared__ unsigned p16[8][128];      // 4 KB f16-paired probs
    __shared__ float4 parts[8][8][32];    // 32 KB pv partials

    int bid = blockIdx.x;
    int dt = bid % 6;
    int qt = (bid / 6) & 31;
    int b  = bid / 192;
    int q0 = qt * 8;
    int t = threadIdx.x;
    int wave = t >> 6, lane = t & 63;

    const float* qP = ws_proj;
    const float* kP = ws_proj + WS_KP;
    const float* eP = ws_proj + WS_EP;
    const unsigned* m16 = (const unsigned*)(ws_proj + WS_M16);

    // ---- hoisted score-phase loads: lm/am for BOTH rows of this wave ----
    int bqA = b * Qn + q0 + wave;         // row rr=0
    int bqB = bqA + 4;                    // row rr=1
    int   lA[4], lB[4];
    float amA[4], amB[4];
    #pragma unroll
    for (int j = 0; j < 4; ++j) {
        int kk = j * 64 + lane;
        lA[j]  = lm[(size_t)bqA * Kn + kk];
        lB[j]  = lm[(size_t)bqB * Kn + kk];
        amA[j] = am[(size_t)bqA * Kn + kk];
        amB[j] = am[(size_t)bqB * Kn + kk];
    }

    // ---- PV mapping + prefetch first two k-pair rows ----
    int kh = t >> 5;
    int c4 = t & 31;
    int d0 = dt * 128 + (c4 << 2);
    const unsigned* mbase = m16 + ((size_t)(b * 128 + kh * 16) * Dn + d0);
    uint4 pA0 = *(const uint4*)(mbase);
    uint4 pB0 = *(const uint4*)(mbase + Dn);
    uint4 pA1 = *(const uint4*)(mbase + 2 * Dn);
    uint4 pB1 = *(const uint4*)(mbase + 3 * Dn);

    float b1v = b1[0];
    float b2v[5] = {b2[0], b2[1], b2[2], b2[3], b2[4]};

    // this block's k-slice for the 5-class scores output
    int slo = dt * 43;
    int shi = (dt == 5) ? 256 : slo + 43;

    // k projections: lane owns k = j*64+lane, j=0..3 (shared by both rows)
    float kp[4][6];
    #pragma unroll
    for (int j = 0; j < 4; ++j) {
        const float* kr = &kP[(b * Kn + j * 64 + lane) * 8];
        float4 a  = *(const float4*)kr;
        float4 bb = *(const float4*)(kr + 4);
        kp[j][0] = a.x; kp[j][1] = a.y; kp[j][2] = a.z;
        kp[j][3] = a.w; kp[j][4] = bb.x; kp[j][5] = bb.y;
    }

    #pragma unroll
    for (int rr = 0; rr < 2; ++rr) {
        int qi = wave + rr * 4;                  // this wave's q-row
        int bq = rr ? bqB : bqA;
        const int*   l   = rr ? lB : lA;
        const float* amv = rr ? amB : amA;
        float qp[6];
        #pragma unroll
        for (int j2 = 0; j2 < 6; ++j2) qp[j2] = qP[bq * 8 + j2];  // uniform

        // no max-shift: |as| bounded, exp safe in f32
        float e[4], sum = 0.f;
        #pragma unroll
        for (int j = 0; j < 4; ++j) {
            float e0 = eP[l[j] * 8];
            float as = (qp[0] + kp[j][0] + e0 + b1v) * amv[j];
            e[j] = __expf(as);
            sum += e[j];
        }
        #pragma unroll
        for (int off = 32; off > 0; off >>= 1)
            sum += __shfl_xor(sum, off, 64);
        float inv = 1.f / sum;
        #pragma unroll
        for (int j = 0; j < 4; ++j) {
            float val = e[j] * inv;
            float nb  = __shfl_down(val, 1, 64);
            if (!(lane & 1))
                p16[qi][(j * 64 + lane) >> 1] = pack_h2(val, nb);
        }

        // 5-class softmax (no max-shift) -> direct store, k-slice [slo,shi)
        #pragma unroll
        for (int j = 0; j < 4; ++j) {
            int kk = j * 64 + lane;
            if (kk >= slo && kk < shi) {
                const float* er = &eP[l[j] * 8];
                float4 ea = *(const float4*)er;
                float4 eb = *(const float4*)(er + 4);
                float epc[5] = {ea.y, ea.z, ea.w, eb.x, eb.y};
                float lg[5];
                float s5 = 0.f;
                #pragma unroll
                for (int c = 0; c < 5; ++c) {
                    lg[c] = __expf(qp[c + 1] + kp[j][c + 1] + epc[c] + b2v[c]);
                    s5 += lg[c];
                }
                float inv5 = 1.f / s5;
                float* so = scores_out + ((size_t)bq * Kn + kk) * 5;
                #pragma unroll
                for (int c = 0; c < 5; ++c) so[c] = lg[c] * inv5;
            }
        }
    }
    __syncthreads();   // p16 complete

    // -------- PV: content[b, q0..q0+7, dt*128..+127] = p @ m (f16 dot2) ----
    float4 acc[8];
    #pragma unroll
    for (int qi = 0; qi < 8; ++qi) acc[qi] = make_float4(0.f, 0.f, 0.f, 0.f);

    #pragma unroll
    for (int g2 = 0; g2 < 8; ++g2) {       // 2 k-pairs (4 k) per iteration
        uint4 A, B;
        if (g2 == 0)      { A = pA0; B = pB0; }
        else if (g2 == 1) { A = pA1; B = pB1; }
        else {
            const unsigned* mb = mbase + (size_t)(2 * g2) * Dn;
            A = *(const uint4*)(mb);
            B = *(const uint4*)(mb + Dn);
        }
        #pragma unroll
        for (int qi = 0; qi < 8; ++qi) {
            uint2 pp = *(const uint2*)&p16[qi][kh * 16 + 2 * g2];
            h2f h0 = bc_h2(pp.x), h1 = bc_h2(pp.y);
            acc[qi].x = __builtin_amdgcn_fdot2(h1, bc_h2(B.x),
                        __builtin_amdgcn_fdot2(h0, bc_h2(A.x), acc[qi].x, false), false);
            acc[qi].y = __builtin_amdgcn_fdot2(h1, bc_h2(B.y),
                        __builtin_amdgcn_fdot2(h0, bc_h2(A.y), acc[qi].y, false), false);
            acc[qi].z = __builtin_amdgcn_fdot2(h1, bc_h2(B.z),
                        __builtin_amdgcn_fdot2(h0, bc_h2(A.z), acc[qi].z, false), false);
            acc[qi].w = __builtin_amdgcn_fdot2(h1, bc_h2(B.w),
                        __builtin_amdgcn_fdot2(h0, bc_h2(A.w), acc[qi].w, false), false);
        }
    }
    #pragma unroll
    for (int qi = 0; qi < 8; ++qi) parts[kh][qi][c4] = acc[qi];
    __syncthreads();

    int qi2 = t >> 5, c42 = t & 31;
    float4 s = parts[0][qi2][c42];
    #pragma unroll
    for (int kk = 1; kk < 8; ++kk) {
        float4 v = parts[kk][qi2][c42];
        s.x += v.x; s.y += v.y; s.z += v.z; s.w += v.w;
    }
    *(float4*)(content_out + (size_t)(b * Qn + q0 + qi2) * Dn + dt * 128 + (c42 << 2)) = s;
}

extern "C" void kernel_launch(void* const* d_in, const int* in_sizes, int n_in,
                              void* d_out, int out_size, void* d_ws, size_t ws_size,
                              hipStream_t stream) {
    const float* q   = (const float*)d_in[0];
    const float* k   = (const float*)d_in[1];
    const float* m   = (const float*)d_in[2];
    const float* am  = (const float*)d_in[3];
    const float* emb = (const float*)d_in[4];
    const float* W1  = (const float*)d_in[5];
    const float* b1  = (const float*)d_in[6];
    const float* W2  = (const float*)d_in[7];
    const float* b2  = (const float*)d_in[8];
    const int*   lm  = (const int*)d_in[9];

    float* out         = (float*)d_out;
    float* out_content = out;                 // [4,256,768]
    float* out_scores  = out + Bn * Qn * Dn;  // [4,256,256,5]

    float* ws = (float*)d_ws;

    proj_kernel<<<537 + 192, 256, 0, stream>>>(q, k, emb, W1, W2, m, ws);
    fused_kernel<<<Bn * (Qn / 8) * 6, 256, 0, stream>>>(
        ws, am, lm, b1, b2, out_scores, out_content);
}

// Round 13
// 22.265 us; speedup vs baseline: 1.0331x; 1.0331x over previous
//
#include <hip/hip_runtime.h>

// Problem: B=4, Q=256, K=256, H=768, D=768, NUM_LEN=100
// s = q + k + emb[lm]  (never materialized; all linear maps distribute)
// ws float layout: qP[1024][8] @0, kP[1024][8] @8192, eP[100][8] @16384
#define Hn 768
#define Bn 4
#define Qn 256
#define Kn 256
#define Dn 768
#define WS_KP 8192
#define WS_EP 16384

typedef float f32x2 __attribute__((ext_vector_type(2)));

// packed f32 fma with broadcast of one half of p to both halves (op_sel).
// acc.lo += p.lo * m.lo ; acc.hi += p.lo * m.hi
__device__ __forceinline__ void pkfma_lo(f32x2& acc, f32x2 p, f32x2 mm) {
    asm("v_pk_fma_f32 %0, %1, %2, %0 op_sel:[0,0,0] op_sel_hi:[0,1,1]"
        : "+v"(acc) : "v"(p), "v"(mm));
}
// acc.lo += p.hi * m.lo ; acc.hi += p.hi * m.hi
__device__ __forceinline__ void pkfma_hi(f32x2& acc, f32x2 p, f32x2 mm) {
    asm("v_pk_fma_f32 %0, %1, %2, %0 op_sel:[1,0,0] op_sel_hi:[1,1,1]"
        : "+v"(acc) : "v"(p), "v"(mm));
}

// ---------------- kernel 1: projections (wave per row; R7/R10 proven) -------
// 537 blocks x 4 waves: parallelism beats weight reuse at this size (R9 lesson)
__global__ __launch_bounds__(256) void proj_kernel(
    const float* __restrict__ q, const float* __restrict__ k,
    const float* __restrict__ emb, const float* __restrict__ W1,
    const float* __restrict__ W2, float* __restrict__ ws)
{
    int wid  = blockIdx.x * 4 + (threadIdx.x >> 6);
    int lane = threadIdx.x & 63;
    const float* src;
    float* dst;
    if (wid < 1024)      { src = q + wid * Hn;            dst = ws + wid * 8; }
    else if (wid < 2048) { src = k + (wid - 1024) * Hn;   dst = ws + WS_KP + (wid - 1024) * 8; }
    else {
        int r = wid - 2048;
        if (r >= 100) return;
        src = emb + r * Hn; dst = ws + WS_EP + r * 8;
    }
    float acc[6] = {0.f, 0.f, 0.f, 0.f, 0.f, 0.f};
    #pragma unroll
    for (int i = 0; i < 3; ++i) {
        int h = i * 256 + lane * 4;
        float4 x  = *(const float4*)&src[h];
        float4 w1 = *(const float4*)&W1[h];
        acc[0] += x.x * w1.x + x.y * w1.y + x.z * w1.z + x.w * w1.w;
        #pragma unroll
        for (int c = 0; c < 5; ++c) {
            float4 w2 = *(const float4*)&W2[c * Hn + h];
            acc[1 + c] += x.x * w2.x + x.y * w2.y + x.z * w2.z + x.w * w2.w;
        }
    }
    #pragma unroll
    for (int j = 0; j < 6; ++j) {
        float v = acc[j];
        #pragma unroll
        for (int off = 32; off > 0; off >>= 1)
            v += __shfl_xor(v, off, 64);
        if (lane == 0) dst[j] = v;
    }
}

// ---------------- kernel 2: fused score + softmax + PV ----------------------
// block = (b:4, qt:32 [8 q rows], dt:6 [128 d cols]) = 768 blocks, 256 thr.
// Score phase: WAVE per q-row (2 rows/wave), all-shfl softmax with NO
// max-subtraction (logits bounded -> exp safe in f32), lm/am hoisted to top.
// 5-class scores balanced across dt-replicas (k-slice [dt*43, ...)).
// PV phase: kh = t>>5 (8 k-groups of 32), c4 = t&31 (float4 d col); first two
// m-tiles prefetched into regs; inner product via v_pk_fma_f32 (2 FMA/inst).
__global__ __launch_bounds__(256, 4) void fused_kernel(
    const float* __restrict__ ws_proj, const float* __restrict__ m,
    const float* __restrict__ am, const int* __restrict__ lm,
    const float* __restrict__ b1, const float* __restrict__ b2,
    float* __restrict__ scores_out, float* __restrict__ content_out)
{
    __shared__ float p[8][Kn];            // 8 KB probs
    __shared__ float4 parts[8][8][32];    // 32 KB pv partials

    int bid = blockIdx.x;
    int dt = bid % 6;
    int qt = (bid / 6) & 31;
    int b  = bid / 192;
    int q0 = qt * 8;
    int t = threadIdx.x;
    int wave = t >> 6, lane = t & 63;

    const float* qP = ws_proj;
    const float* kP = ws_proj + WS_KP;
    const float* eP = ws_proj + WS_EP;

    // ---- hoisted score-phase loads: lm/am for BOTH rows of this wave ----
    int bqA = b * Qn + q0 + wave;         // row rr=0
    int bqB = bqA + 4;                    // row rr=1
    int   lA[4], lB[4];
    float amA[4], amB[4];
    #pragma unroll
    for (int j = 0; j < 4; ++j) {
        int kk = j * 64 + lane;
        lA[j]  = lm[(size_t)bqA * Kn + kk];
        lB[j]  = lm[(size_t)bqB * Kn + kk];
        amA[j] = am[(size_t)bqA * Kn + kk];
        amB[j] = am[(size_t)bqB * Kn + kk];
    }

    // ---- PV prefetch: first two m-tiles (g=0,1) into registers ----
    int kh = t >> 5;
    int c4 = t & 31;
    const float* mb0 = m + (size_t)(b * Kn + (kh << 5)) * Dn + dt * 128 + (c4 << 2);
    float4 pm0 = *(const float4*)(mb0);
    float4 pm1 = *(const float4*)(mb0 + Dn);
    float4 pm2 = *(const float4*)(mb0 + 2 * Dn);
    float4 pm3 = *(const float4*)(mb0 + 3 * Dn);
    float4 pm4 = *(const float4*)(mb0 + 4 * Dn);
    float4 pm5 = *(const float4*)(mb0 + 5 * Dn);
    float4 pm6 = *(const float4*)(mb0 + 6 * Dn);
    float4 pm7 = *(const float4*)(mb0 + 7 * Dn);

    float b1v = b1[0];
    float b2v[5] = {b2[0], b2[1], b2[2], b2[3], b2[4]};

    // this block's k-slice for the 5-class scores output
    int slo = dt * 43;
    int shi = (dt == 5) ? 256 : slo + 43;

    // k projections: lane owns k = j*64+lane, j=0..3 (shared by both rows)
    float kp[4][6];
    #pragma unroll
    for (int j = 0; j < 4; ++j) {
        const float* kr = &kP[(b * Kn + j * 64 + lane) * 8];
        float4 a  = *(const float4*)kr;
        float4 bb = *(const float4*)(kr + 4);
        kp[j][0] = a.x; kp[j][1] = a.y; kp[j][2] = a.z;
        kp[j][3] = a.w; kp[j][4] = bb.x; kp[j][5] = bb.y;
    }

    #pragma unroll
    for (int rr = 0; rr < 2; ++rr) {
        int qi = wave + rr * 4;                  // this wave's q-row
        int bq = rr ? bqB : bqA;
        const int*   l   = rr ? lB : lA;
        const float* amv = rr ? amB : amA;
        float qp[6];
        #pragma unroll
        for (int j2 = 0; j2 < 6; ++j2) qp[j2] = qP[bq * 8 + j2];  // uniform

        // no max-shift: |as| bounded (~N(0,2) * am<1), exp safe in f32
        float e[4], sum = 0.f;
        #pragma unroll
        for (int j = 0; j < 4; ++j) {
            float e0 = eP[l[j] * 8];
            float as = (qp[0] + kp[j][0] + e0 + b1v) * amv[j];
            e[j] = __expf(as);
            sum += e[j];
        }
        #pragma unroll
        for (int off = 32; off > 0; off >>= 1)
            sum += __shfl_xor(sum, off, 64);
        float inv = 1.f / sum;
        #pragma unroll
        for (int j = 0; j < 4; ++j) p[qi][j * 64 + lane] = e[j] * inv;

        // 5-class softmax (no max-shift) -> direct store, k-slice [slo,shi)
        #pragma unroll
        for (int j = 0; j < 4; ++j) {
            int kk = j * 64 + lane;
            if (kk >= slo && kk < shi) {
                const float* er = &eP[l[j] * 8];
                float4 ea = *(const float4*)er;
                float4 eb = *(const float4*)(er + 4);
                float epc[5] = {ea.y, ea.z, ea.w, eb.x, eb.y};
                float lg[5];
                float s5 = 0.f;
                #pragma unroll
                for (int c = 0; c < 5; ++c) {
                    lg[c] = __expf(qp[c + 1] + kp[j][c + 1] + epc[c] + b2v[c]);
                    s5 += lg[c];
                }
                float inv5 = 1.f / s5;
                float* so = scores_out + ((size_t)bq * Kn + kk) * 5;
                #pragma unroll
                for (int c = 0; c < 5; ++c) so[c] = lg[c] * inv5;
            }
        }
    }
    __syncthreads();   // p complete

    // -------- PV: content[b, q0..q0+7, dt*128..+127] = p @ m ---------------
    f32x2 accA[8], accB[8];
    #pragma unroll
    for (int qi = 0; qi < 8; ++qi) {
        accA[qi] = (f32x2){0.f, 0.f};
        accB[qi] = (f32x2){0.f, 0.f};
    }

    #pragma unroll
    for (int g = 0; g < 8; ++g) {
        int k0 = (kh << 5) + (g << 2);
        float4 m0, m1, m2, m3;
        if (g == 0)      { m0 = pm0; m1 = pm1; m2 = pm2; m3 = pm3; }
        else if (g == 1) { m0 = pm4; m1 = pm5; m2 = pm6; m3 = pm7; }
        else {
            const float* mb = m + (size_t)(b * Kn + k0) * Dn + dt * 128 + (c4 << 2);
            m0 = *(const float4*)(mb);
            m1 = *(const float4*)(mb + Dn);
            m2 = *(const float4*)(mb + 2 * Dn);
            m3 = *(const float4*)(mb + 3 * Dn);
        }
        f32x2 m0A = {m0.x, m0.y}, m0B = {m0.z, m0.w};
        f32x2 m1A = {m1.x, m1.y}, m1B = {m1.z, m1.w};
        f32x2 m2A = {m2.x, m2.y}, m2B = {m2.z, m2.w};
        f32x2 m3A = {m3.x, m3.y}, m3B = {m3.z, m3.w};
        #pragma unroll
        for (int qi = 0; qi < 8; ++qi) {
            float4 pv = *(const float4*)&p[qi][k0];   // 2-addr broadcast read
            f32x2 p01 = {pv.x, pv.y};
            f32x2 p23 = {pv.z, pv.w};
            pkfma_lo(accA[qi], p01, m0A); pkfma_lo(accB[qi], p01, m0B);
            pkfma_hi(accA[qi], p01, m1A); pkfma_hi(accB[qi], p01, m1B);
            pkfma_lo(accA[qi], p23, m2A); pkfma_lo(accB[qi], p23, m2B);
            pkfma_hi(accA[qi], p23, m3A); pkfma_hi(accB[qi], p23, m3B);
        }
    }
    #pragma unroll
    for (int qi = 0; qi < 8; ++qi) {
        float4 v;
        v.x = accA[qi][0]; v.y = accA[qi][1];
        v.z = accB[qi][0]; v.w = accB[qi][1];
        parts[kh][qi][c4] = v;
    }
    __syncthreads();

    int qi2 = t >> 5, c42 = t & 31;
    float4 s = parts[0][qi2][c42];
    #pragma unroll
    for (int kk = 1; kk < 8; ++kk) {
        float4 v = parts[kk][qi2][c42];
        s.x += v.x; s.y += v.y; s.z += v.z; s.w += v.w;
    }
    *(float4*)(content_out + (size_t)(b * Qn + q0 + qi2) * Dn + dt * 128 + (c42 << 2)) = s;
}

extern "C" void kernel_launch(void* const* d_in, const int* in_sizes, int n_in,
                              void* d_out, int out_size, void* d_ws, size_t ws_size,
                              hipStream_t stream) {
    const float* q   = (const float*)d_in[0];
    const float* k   = (const float*)d_in[1];
    const float* m   = (const float*)d_in[2];
    const float* am  = (const float*)d_in[3];
    const float* emb = (const float*)d_in[4];
    const float* W1  = (const float*)d_in[5];
    const float* b1  = (const float*)d_in[6];
    const float* W2  = (const float*)d_in[7];
    const float* b2  = (const float*)d_in[8];
    const int*   lm  = (const int*)d_in[9];

    float* out         = (float*)d_out;
    float* out_content = out;                 // [4,256,768]
    float* out_scores  = out + Bn * Qn * Dn;  // [4,256,256,5]

    float* ws = (float*)d_ws;

    proj_kernel<<<537, 256, 0, stream>>>(q, k, emb, W1, W2, ws);
    fused_kernel<<<Bn * (Qn / 8) * 6, 256, 0, stream>>>(
        ws, m, am, lm, b1, b2, out_scores, out_content);
}